// Round 3
// baseline (153.316 us; speedup 1.0000x reference)
//
#include <hip/hip_runtime.h>

// IIR filter bank: B=16, T=32768, F=30, order 6 (K=7).
// Overlap-and-discard chunking (poles |p|<=0.95; WARM=384 -> 0.95^384~3e-9
// state truncation, negligible vs threshold). One thread per (b,f,chunk).
// R1: deep software prefetch (32 samples ahead) to hide ~200cy L2 latency
// that dominated R0 (VALUBusy 21%, latency-bound); WARM 512->384; NT stores.
// R2: NT store via ext_vector_type (builtin rejects HIP_vector_type).

#define BB 16
#define TT 32768
#define FF 30
#define KK 7
#define ORD 6
#define CHUNK 256
#define WARM 384
#define NCHUNK (TT / CHUNK)  // 128

typedef float vfloat4 __attribute__((ext_vector_type(4)));

// Transposed direct-form II step: 13 FMAs, no state shifting.
__device__ __forceinline__ float iir_step(float xv, float st[ORD],
                                          const float bc[KK],
                                          const float ac[ORD]) {
    float y = fmaf(bc[0], xv, st[0]);
#pragma unroll
    for (int j = 0; j < ORD - 1; ++j)
        st[j] = fmaf(-ac[j], y, fmaf(bc[j + 1], xv, st[j + 1]));
    st[ORD - 1] = fmaf(-ac[ORD - 1], y, bc[KK - 1] * xv);
    return y;
}

__device__ __forceinline__ void load16(const float* __restrict__ p,
                                       float4 v[4]) {
#pragma unroll
    for (int q = 0; q < 4; ++q)
        v[q] = *reinterpret_cast<const float4*>(p + 4 * q);
}

template <bool STORE>
__device__ __forceinline__ void proc16(const float4 v[4], float st[ORD],
                                       const float bc[KK], const float ac[ORD],
                                       float* __restrict__ op) {
#pragma unroll
    for (int q = 0; q < 4; ++q) {
        vfloat4 y;
        y.x = iir_step(v[q].x, st, bc, ac);
        y.y = iir_step(v[q].y, st, bc, ac);
        y.z = iir_step(v[q].z, st, bc, ac);
        y.w = iir_step(v[q].w, st, bc, ac);
        if (STORE)
            __builtin_nontemporal_store(
                y, reinterpret_cast<vfloat4*>(op + 4 * q));
    }
}

__global__ __launch_bounds__(256) void iir_chunked_kernel(
    const float* __restrict__ x,    // [B][T]
    const float* __restrict__ bs,   // [F][K]
    const float* __restrict__ as_,  // [F][K]
    float* __restrict__ out)        // [B][F][T]
{
    const int tid = blockIdx.x * blockDim.x + threadIdx.x;
    // f fastest: lanes in a wave mostly share (b, chunk) -> broadcast x loads
    const int f = tid % FF;
    const int rest = tid / FF;
    const int chunk = rest % NCHUNK;
    const int b = rest / NCHUNK;

    const float inv_a0 = 1.0f / as_[f * KK];
    float bc[KK], ac[ORD];
#pragma unroll
    for (int j = 0; j < KK; ++j) bc[j] = bs[f * KK + j] * inv_a0;
#pragma unroll
    for (int j = 0; j < ORD; ++j) ac[j] = as_[f * KK + 1 + j] * inv_a0;

    const float* __restrict__ xrow = x + b * TT;
    const int t0 = chunk * CHUNK;
    int ws = t0 - WARM;
    if (ws < 0) ws = 0;  // ws is a multiple of 128 -> 16B-aligned loads

    float st[ORD];
#pragma unroll
    for (int j = 0; j < ORD; ++j) st[j] = 0.0f;

    // Prime the double buffer: A=[ws,ws+16), B=[ws+16,ws+32).
    float4 A[4], B[4];
    load16(xrow + ws, A);
    load16(xrow + ws + 16, B);

    // Warm-up (length 0, 256, or 384 -> multiple of 32). Prefetch next 32
    // samples before consuming current 32: 200cy L2 latency hides under
    // ~256cy of dependent-FMA chain.
    for (int t = ws; t < t0; t += 32) {
        float4 NA[4], NB[4];
        load16(xrow + t + 32, NA);  // max addr: t0+32 <= 32544, in-bounds
        load16(xrow + t + 48, NB);
        proc16<false>(A, st, bc, ac, nullptr);
        proc16<false>(B, st, bc, ac, nullptr);
#pragma unroll
        for (int q = 0; q < 4; ++q) { A[q] = NA[q]; B[q] = NB[q]; }
    }

    // Output phase: 8 iterations of 32 samples, same prefetch structure.
    float* __restrict__ orow = out + (b * FF + f) * TT;
#pragma unroll
    for (int i = 0; i < CHUNK / 32; ++i) {
        const int t = t0 + 32 * i;
        int pf = t + 32;
        if (pf > TT - 32) pf = TT - 32;  // clamp final prefetch (chunk 127)
        float4 NA[4], NB[4];
        load16(xrow + pf, NA);
        load16(xrow + pf + 16, NB);
        proc16<true>(A, st, bc, ac, orow + t);
        proc16<true>(B, st, bc, ac, orow + t + 16);
#pragma unroll
        for (int q = 0; q < 4; ++q) { A[q] = NA[q]; B[q] = NB[q]; }
    }
}

extern "C" void kernel_launch(void* const* d_in, const int* in_sizes, int n_in,
                              void* d_out, int out_size, void* d_ws,
                              size_t ws_size, hipStream_t stream) {
    const float* x   = (const float*)d_in[0];
    const float* bs  = (const float*)d_in[1];
    const float* as_ = (const float*)d_in[2];
    float* out = (float*)d_out;

    const int total = BB * FF * NCHUNK;  // 61440 threads = 960 waves
    const int block = 256;
    const int grid = total / block;      // 240
    hipLaunchKernelGGL(iir_chunked_kernel, dim3(grid), dim3(block), 0, stream,
                       x, bs, as_, out);
}

// Round 4
// 41.500 us; speedup vs baseline: 3.6944x; 3.6944x over previous
//
#include <hip/hip_runtime.h>

// IIR filter bank: B=16, T=32768, F=30, order 6 (K=7).
// Overlap-and-discard chunking (poles |p|<=0.95; WARM=384 -> 0.95^384~3e-9
// state truncation, negligible vs threshold). One thread per (b,f,chunk).
// R1: deep software prefetch (32 samples ahead) to hide ~200cy L2 latency
//     that dominated R0 (VALUBusy 21%, latency-bound); WARM 512->384.
// R3: REVERTED nontemporal stores (R2: WRITE_SIZE 62->189 MB, 3x write
//     amplification — per-lane lines need L2 store-merging; lanes write
//     rows 128KB apart so one instruction never covers a whole line).

#define BB 16
#define TT 32768
#define FF 30
#define KK 7
#define ORD 6
#define CHUNK 256
#define WARM 384
#define NCHUNK (TT / CHUNK)  // 128

// Transposed direct-form II step: 13 FMAs, no state shifting.
__device__ __forceinline__ float iir_step(float xv, float st[ORD],
                                          const float bc[KK],
                                          const float ac[ORD]) {
    float y = fmaf(bc[0], xv, st[0]);
#pragma unroll
    for (int j = 0; j < ORD - 1; ++j)
        st[j] = fmaf(-ac[j], y, fmaf(bc[j + 1], xv, st[j + 1]));
    st[ORD - 1] = fmaf(-ac[ORD - 1], y, bc[KK - 1] * xv);
    return y;
}

__device__ __forceinline__ void load16(const float* __restrict__ p,
                                       float4 v[4]) {
#pragma unroll
    for (int q = 0; q < 4; ++q)
        v[q] = *reinterpret_cast<const float4*>(p + 4 * q);
}

template <bool STORE>
__device__ __forceinline__ void proc16(const float4 v[4], float st[ORD],
                                       const float bc[KK], const float ac[ORD],
                                       float* __restrict__ op) {
#pragma unroll
    for (int q = 0; q < 4; ++q) {
        float4 y;
        y.x = iir_step(v[q].x, st, bc, ac);
        y.y = iir_step(v[q].y, st, bc, ac);
        y.z = iir_step(v[q].z, st, bc, ac);
        y.w = iir_step(v[q].w, st, bc, ac);
        if (STORE)
            *reinterpret_cast<float4*>(op + 4 * q) = y;  // cached: L2 merges
    }
}

__global__ __launch_bounds__(256) void iir_chunked_kernel(
    const float* __restrict__ x,    // [B][T]
    const float* __restrict__ bs,   // [F][K]
    const float* __restrict__ as_,  // [F][K]
    float* __restrict__ out)        // [B][F][T]
{
    const int tid = blockIdx.x * blockDim.x + threadIdx.x;
    // f fastest: lanes in a wave mostly share (b, chunk) -> broadcast x loads
    const int f = tid % FF;
    const int rest = tid / FF;
    const int chunk = rest % NCHUNK;
    const int b = rest / NCHUNK;

    const float inv_a0 = 1.0f / as_[f * KK];
    float bc[KK], ac[ORD];
#pragma unroll
    for (int j = 0; j < KK; ++j) bc[j] = bs[f * KK + j] * inv_a0;
#pragma unroll
    for (int j = 0; j < ORD; ++j) ac[j] = as_[f * KK + 1 + j] * inv_a0;

    const float* __restrict__ xrow = x + b * TT;
    const int t0 = chunk * CHUNK;
    int ws = t0 - WARM;
    if (ws < 0) ws = 0;  // ws is a multiple of 128 -> 16B-aligned loads

    float st[ORD];
#pragma unroll
    for (int j = 0; j < ORD; ++j) st[j] = 0.0f;

    // Prime the double buffer: A=[ws,ws+16), B=[ws+16,ws+32).
    float4 A[4], B[4];
    load16(xrow + ws, A);
    load16(xrow + ws + 16, B);

    // Warm-up (length 0, 256, or 384 -> multiple of 32). Prefetch next 32
    // samples before consuming current 32: 200cy L2 latency hides under
    // ~256cy of dependent-FMA chain.
    for (int t = ws; t < t0; t += 32) {
        float4 NA[4], NB[4];
        load16(xrow + t + 32, NA);  // max addr: t0+32 <= 32544, in-bounds
        load16(xrow + t + 48, NB);
        proc16<false>(A, st, bc, ac, nullptr);
        proc16<false>(B, st, bc, ac, nullptr);
#pragma unroll
        for (int q = 0; q < 4; ++q) { A[q] = NA[q]; B[q] = NB[q]; }
    }

    // Output phase: 8 iterations of 32 samples, same prefetch structure.
    float* __restrict__ orow = out + (b * FF + f) * TT;
#pragma unroll
    for (int i = 0; i < CHUNK / 32; ++i) {
        const int t = t0 + 32 * i;
        int pf = t + 32;
        if (pf > TT - 32) pf = TT - 32;  // clamp final prefetch (chunk 127)
        float4 NA[4], NB[4];
        load16(xrow + pf, NA);
        load16(xrow + pf + 16, NB);
        proc16<true>(A, st, bc, ac, orow + t);
        proc16<true>(B, st, bc, ac, orow + t + 16);
#pragma unroll
        for (int q = 0; q < 4; ++q) { A[q] = NA[q]; B[q] = NB[q]; }
    }
}

extern "C" void kernel_launch(void* const* d_in, const int* in_sizes, int n_in,
                              void* d_out, int out_size, void* d_ws,
                              size_t ws_size, hipStream_t stream) {
    const float* x   = (const float*)d_in[0];
    const float* bs  = (const float*)d_in[1];
    const float* as_ = (const float*)d_in[2];
    float* out = (float*)d_out;

    const int total = BB * FF * NCHUNK;  // 61440 threads = 960 waves
    const int block = 256;
    const int grid = total / block;      // 240
    hipLaunchKernelGGL(iir_chunked_kernel, dim3(grid), dim3(block), 0, stream,
                       x, bs, as_, out);
}

// Round 5
// 36.361 us; speedup vs baseline: 4.2165x; 1.1413x over previous
//
#include <hip/hip_runtime.h>

// IIR filter bank: B=16, T=32768, F=30, order 6 (K=7).
// Overlap-and-discard chunking. One thread per (b,f,chunk).
// R3: cached float4 stores (NT stores = 3x write amplification, lanes write
//     rows 128KB apart; L2 must merge per-lane 16B stores into lines).
// R4: CHUNK 256->128, WARM 384->256. R3 showed 960 waves < 1024 SIMDs
//     (Occupancy 8%, VALUBusy 25%, VGPR=44 -> compiler dropped the prefetch
//     buffers anyway). TLP, not intra-thread pipelining, is the lever:
//     1920 waves = 2/SIMD. 0.95^256 ~ 2e-6 truncation, fine vs thr 9.96.

#define BB 16
#define TT 32768
#define FF 30
#define KK 7
#define ORD 6
#define CHUNK 128
#define WARM 256
#define NCHUNK (TT / CHUNK)  // 256

// Transposed direct-form II step: 13 FMAs, no state shifting.
__device__ __forceinline__ float iir_step(float xv, float st[ORD],
                                          const float bc[KK],
                                          const float ac[ORD]) {
    float y = fmaf(bc[0], xv, st[0]);
#pragma unroll
    for (int j = 0; j < ORD - 1; ++j)
        st[j] = fmaf(-ac[j], y, fmaf(bc[j + 1], xv, st[j + 1]));
    st[ORD - 1] = fmaf(-ac[ORD - 1], y, bc[KK - 1] * xv);
    return y;
}

__device__ __forceinline__ void load16(const float* __restrict__ p,
                                       float4 v[4]) {
#pragma unroll
    for (int q = 0; q < 4; ++q)
        v[q] = *reinterpret_cast<const float4*>(p + 4 * q);
}

template <bool STORE>
__device__ __forceinline__ void proc16(const float4 v[4], float st[ORD],
                                       const float bc[KK], const float ac[ORD],
                                       float* __restrict__ op) {
#pragma unroll
    for (int q = 0; q < 4; ++q) {
        float4 y;
        y.x = iir_step(v[q].x, st, bc, ac);
        y.y = iir_step(v[q].y, st, bc, ac);
        y.z = iir_step(v[q].z, st, bc, ac);
        y.w = iir_step(v[q].w, st, bc, ac);
        if (STORE)
            *reinterpret_cast<float4*>(op + 4 * q) = y;  // cached: L2 merges
    }
}

__global__ __launch_bounds__(256) void iir_chunked_kernel(
    const float* __restrict__ x,    // [B][T]
    const float* __restrict__ bs,   // [F][K]
    const float* __restrict__ as_,  // [F][K]
    float* __restrict__ out)        // [B][F][T]
{
    const int tid = blockIdx.x * blockDim.x + threadIdx.x;
    // f fastest: lanes in a wave mostly share (b, chunk) -> broadcast x loads
    const int f = tid % FF;
    const int rest = tid / FF;
    const int chunk = rest % NCHUNK;
    const int b = rest / NCHUNK;

    const float inv_a0 = 1.0f / as_[f * KK];
    float bc[KK], ac[ORD];
#pragma unroll
    for (int j = 0; j < KK; ++j) bc[j] = bs[f * KK + j] * inv_a0;
#pragma unroll
    for (int j = 0; j < ORD; ++j) ac[j] = as_[f * KK + 1 + j] * inv_a0;

    const float* __restrict__ xrow = x + b * TT;
    const int t0 = chunk * CHUNK;
    int ws = t0 - WARM;
    if (ws < 0) ws = 0;  // ws is a multiple of 128 -> 16B-aligned loads

    float st[ORD];
#pragma unroll
    for (int j = 0; j < ORD; ++j) st[j] = 0.0f;

    // Prime the double buffer: A=[ws,ws+16), B=[ws+16,ws+32).
    float4 A[4], B[4];
    load16(xrow + ws, A);
    load16(xrow + ws + 16, B);

    // Warm-up (length 0, 128, or 256 -> multiple of 32). Prefetch next 32
    // samples before consuming current 32.
    for (int t = ws; t < t0; t += 32) {
        float4 NA[4], NB[4];
        load16(xrow + t + 32, NA);
        load16(xrow + t + 48, NB);
        proc16<false>(A, st, bc, ac, nullptr);
        proc16<false>(B, st, bc, ac, nullptr);
#pragma unroll
        for (int q = 0; q < 4; ++q) { A[q] = NA[q]; B[q] = NB[q]; }
    }

    // Output phase: 4 iterations of 32 samples, same prefetch structure.
    float* __restrict__ orow = out + (b * FF + f) * TT;
#pragma unroll
    for (int i = 0; i < CHUNK / 32; ++i) {
        const int t = t0 + 32 * i;
        int pf = t + 32;
        if (pf > TT - 32) pf = TT - 32;  // clamp final prefetch (last chunk)
        float4 NA[4], NB[4];
        load16(xrow + pf, NA);
        load16(xrow + pf + 16, NB);
        proc16<true>(A, st, bc, ac, orow + t);
        proc16<true>(B, st, bc, ac, orow + t + 16);
#pragma unroll
        for (int q = 0; q < 4; ++q) { A[q] = NA[q]; B[q] = NB[q]; }
    }
}

extern "C" void kernel_launch(void* const* d_in, const int* in_sizes, int n_in,
                              void* d_out, int out_size, void* d_ws,
                              size_t ws_size, hipStream_t stream) {
    const float* x   = (const float*)d_in[0];
    const float* bs  = (const float*)d_in[1];
    const float* as_ = (const float*)d_in[2];
    float* out = (float*)d_out;

    const int total = BB * FF * NCHUNK;  // 122880 threads = 1920 waves
    const int block = 256;
    const int grid = total / block;      // 480
    hipLaunchKernelGGL(iir_chunked_kernel, dim3(grid), dim3(block), 0, stream,
                       x, bs, as_, out);
}